// Round 6
// baseline (2414.475 us; speedup 1.0000x reference)
//
#include <hip/hip_runtime.h>
#include <math.h>

#define BATCH 64
#define TLEN 512
#define EMB 256
#define HID 256          // per-direction hidden
#define G4 1024          // 4*HID
#define KTAG 12
#define START_TAG 10
#define STOP_TAG 11
#define NEGV -10000.0f
#define SENT 0xFFFFFFFFu // -NaN sentinel: tanh-bounded h can never be this

#define LOG2E 1.4426950408889634f

__device__ __forceinline__ float fsig(float x) {
    return __builtin_amdgcn_rcpf(1.f + __builtin_amdgcn_exp2f(-LOG2E * x));
}
__device__ __forceinline__ float ftanh(float x) {
    return 1.f - 2.f * __builtin_amdgcn_rcpf(1.f + __builtin_amdgcn_exp2f(2.f * LOG2E * x));
}
__device__ __forceinline__ void st_llc(float* p, float v) {
    __hip_atomic_store(p, v, __ATOMIC_RELAXED, __HIP_MEMORY_SCOPE_AGENT);
}
__device__ __forceinline__ unsigned ld_llc_u(const unsigned* p) {
    return __hip_atomic_load(p, __ATOMIC_RELAXED, __HIP_MEMORY_SCOPE_AGENT);
}

// ---------------------------------------------------------------------------
// K1: fused embedding gather + input projection, both directions.
// x layout: x[r][gate*256+j], r = b*512+t. float4 epilogue stores.
// ---------------------------------------------------------------------------
#define MT 128
#define NT 128
#define KC 32
#define LDP 132

__global__ __launch_bounds__(256) void proj_kernel(
    const int* __restrict__ sentence, const float* __restrict__ emb,
    const float* __restrict__ Wf_ih, const float* __restrict__ Wb_ih,
    const float* __restrict__ bf_ih, const float* __restrict__ bf_hh,
    const float* __restrict__ bb_ih, const float* __restrict__ bb_hh,
    float* __restrict__ xf, float* __restrict__ xb) {
    int mtile = blockIdx.x;
    int ntile = blockIdx.y;
    int tid = threadIdx.x;

    __shared__ float As[KC][LDP];
    __shared__ float Bs[KC][LDP];
    __shared__ int tok[MT];

    int g2base = ntile * NT;
    const bool fwd = (g2base < 1024);
    const float* Wih = fwd ? Wf_ih : Wb_ih;
    const float* bia = fwd ? bf_ih : bb_ih;
    const float* bib = fwd ? bf_hh : bb_hh;
    float* dst       = fwd ? xf    : xb;
    int glb = g2base & 1023;

    if (tid < MT) tok[tid] = sentence[(size_t)mtile * MT + tid];
    __syncthreads();

    float acc[8][8];
#pragma unroll
    for (int i = 0; i < 8; ++i)
#pragma unroll
        for (int jj = 0; jj < 8; ++jj) acc[i][jj] = 0.f;

    int m0 = (tid & 15) * 8;
    int n0 = (tid >> 4) * 8;
    int lr = tid >> 3;
    int lk = (tid & 7) * 4;

    for (int k0 = 0; k0 < EMB; k0 += KC) {
#pragma unroll
        for (int i = 0; i < 4; ++i) {
            int r = lr + 32 * i;
            float4 v = *(const float4*)(emb + (size_t)tok[r] * EMB + k0 + lk);
            As[lk + 0][r] = v.x; As[lk + 1][r] = v.y;
            As[lk + 2][r] = v.z; As[lk + 3][r] = v.w;
            float4 w = *(const float4*)(Wih + (size_t)(glb + r) * EMB + k0 + lk);
            Bs[lk + 0][r] = w.x; Bs[lk + 1][r] = w.y;
            Bs[lk + 2][r] = w.z; Bs[lk + 3][r] = w.w;
        }
        __syncthreads();
#pragma unroll
        for (int kk = 0; kk < KC; ++kk) {
            float4 a0 = *(const float4*)&As[kk][m0];
            float4 a1 = *(const float4*)&As[kk][m0 + 4];
            float4 b0 = *(const float4*)&Bs[kk][n0];
            float4 b1 = *(const float4*)&Bs[kk][n0 + 4];
            float av[8] = {a0.x, a0.y, a0.z, a0.w, a1.x, a1.y, a1.z, a1.w};
            float bv[8] = {b0.x, b0.y, b0.z, b0.w, b1.x, b1.y, b1.z, b1.w};
#pragma unroll
            for (int i = 0; i < 8; ++i)
#pragma unroll
                for (int jj = 0; jj < 8; ++jj) acc[i][jj] += av[i] * bv[jj];
        }
        __syncthreads();
    }

    float bs[8];
#pragma unroll
    for (int jj = 0; jj < 8; ++jj) {
        int gl = glb + n0 + jj;
        bs[jj] = bia[gl] + bib[gl];
    }
#pragma unroll
    for (int i = 0; i < 8; ++i) {
        size_t r = (size_t)mtile * MT + m0 + i;
        float4 s0 = {acc[i][0] + bs[0], acc[i][1] + bs[1],
                     acc[i][2] + bs[2], acc[i][3] + bs[3]};
        float4 s1 = {acc[i][4] + bs[4], acc[i][5] + bs[5],
                     acc[i][6] + bs[6], acc[i][7] + bs[7]};
        *(float4*)(dst + r * (size_t)G4 + glb + n0)     = s0;
        *(float4*)(dst + r * (size_t)G4 + glb + n0 + 4) = s1;
    }
}

// ---------------------------------------------------------------------------
// K2: cooperative LSTM scan v6.
// v5 + VOLATILE W loads. v4/v5 both showed VGPR_Count=84: loads from the
// const __restrict__ arg are marked no-clobber -> the register allocator
// REMATERIALIZES them inside the K-loop (re-streaming 128 KB/block/step from
// L2, ~1.2 us/step) instead of keeping 128 floats live. Volatile loads cannot
// be remat'd/duplicated -> RA must allocate (~210 VGPRs, budget 512 via
// launch_bounds(256,1)). Verification: VGPR_Count must jump to >=190.
// ---------------------------------------------------------------------------
__global__ __launch_bounds__(256, 1) void lstm_scan6(
    const float* __restrict__ xf, const float* __restrict__ xb,
    const float* __restrict__ Wf_hh, const float* __restrict__ Wb_hh,
    float* __restrict__ hcat) {
    int blk = blockIdx.x;
    int grp = blk & 31;          // members of a group share blk%8 (XCD heur.)
    int s   = blk >> 5;          // J-slice 0..7
    int d   = grp >> 4;          // direction
    int gq  = grp & 15;          // batch quartet
    int b0  = gq * 4;
    int tid = threadIdx.x;
    int kseg = tid & 7;
    int j    = tid >> 3;
    int J    = s * 32 + j;
    int bown = kseg & 3;

    // --- W: 4 gate-rows of J, k-slice [kseg*32, +32), via volatile loads ---
    const float* Whh = d ? Wb_hh : Wf_hh;
    float4 Wr[4][8];
#pragma unroll
    for (int g = 0; g < 4; ++g) {
        const volatile float* vb = Whh + (size_t)(g * 256 + J) * 256 + kseg * 32;
#pragma unroll
        for (int q = 0; q < 8; ++q) {
            float4 w;
            w.x = vb[q * 4 + 0];
            w.y = vb[q * 4 + 1];
            w.z = vb[q * 4 + 2];
            w.w = vb[q * 4 + 3];
            Wr[g][q] = w;
        }
    }

    const float* x = d ? xb : xf;
    const float* xrow0 = x + (size_t)(b0 + bown) * TLEN * G4 + J;

    __shared__ float hsL[4 * 288];   // [bb][8 chunks x 36] swizzled
    int sw = (tid >> 5) * 36 + (tid & 31);
    float c = 0.f;

    for (int i = 0; i < TLEN; ++i) {
        int t = d ? (TLEN - 1 - i) : i;

        // prefetch own x gate pre-acts (independent of peers)
        const float* xr = xrow0 + (size_t)t * G4;
        float x0 = xr[0], x1 = xr[256], x2 = xr[512], x3 = xr[768];

        if (i == 0) {
#pragma unroll
            for (int bb = 0; bb < 4; ++bb) hsL[bb * 288 + sw] = 0.f;
        } else {
            int tp = d ? (t + 1) : (t - 1);
            const unsigned* base = (const unsigned*)hcat +
                ((size_t)tp * BATCH + b0) * 512 + (size_t)d * HID + tid;
            unsigned u0, u1, u2, u3;
            for (;;) {
                u0 = ld_llc_u(base);
                u1 = ld_llc_u(base + 512);
                u2 = ld_llc_u(base + 1024);
                u3 = ld_llc_u(base + 1536);
                if (u0 != SENT && u1 != SENT && u2 != SENT && u3 != SENT) break;
                __builtin_amdgcn_s_sleep(1);
            }
            hsL[0 * 288 + sw] = __uint_as_float(u0);
            hsL[1 * 288 + sw] = __uint_as_float(u1);
            hsL[2 * 288 + sw] = __uint_as_float(u2);
            hsL[3 * 288 + sw] = __uint_as_float(u3);
        }
        __syncthreads();

#pragma unroll
        for (int bb = 0; bb < 4; ++bb) {
            const float* hb = hsL + bb * 288 + kseg * 36;
            float a0 = 0.f, a1 = 0.f, a2 = 0.f, a3 = 0.f;
#pragma unroll
            for (int q = 0; q < 8; ++q) {
                float4 h4 = *(const float4*)(hb + q * 4);
                float4 w;
                w = Wr[0][q]; a0 += w.x*h4.x + w.y*h4.y + w.z*h4.z + w.w*h4.w;
                w = Wr[1][q]; a1 += w.x*h4.x + w.y*h4.y + w.z*h4.z + w.w*h4.w;
                w = Wr[2][q]; a2 += w.x*h4.x + w.y*h4.y + w.z*h4.z + w.w*h4.w;
                w = Wr[3][q]; a3 += w.x*h4.x + w.y*h4.y + w.z*h4.z + w.w*h4.w;
            }
#pragma unroll
            for (int m = 1; m <= 4; m <<= 1) {
                a0 += __shfl_xor(a0, m);
                a1 += __shfl_xor(a1, m);
                a2 += __shfl_xor(a2, m);
                a3 += __shfl_xor(a3, m);
            }
            // owner lanes finish this batch NOW and publish h immediately
            if (bb == bown) {
                float ig = fsig(a0 + x0);
                float fg = fsig(a1 + x1);
                float gg = ftanh(a2 + x2);
                float og = fsig(a3 + x3);
                c = fg * c + ig * gg;
                float h = og * ftanh(c);
                if (kseg < 4)
                    st_llc(hcat + ((size_t)t * BATCH + b0 + bown) * 512
                                + (size_t)d * HID + J, h);
            }
        }
        __syncthreads();     // hsL reads done before next restage
    }
}

// ---------------------------------------------------------------------------
// K3: feats[t,b,k] = hcat[t,b,:] . W_out[k,:] + b_out[k].
// ---------------------------------------------------------------------------
__global__ __launch_bounds__(256) void feats_kernel(
    const float* __restrict__ hcat, const float* __restrict__ Wout,
    const float* __restrict__ bout, float* __restrict__ feats) {
    int wid = threadIdx.x >> 6;
    int lane = threadIdx.x & 63;
    size_t row = (size_t)blockIdx.x * 4 + wid;
    const float* hrow = hcat + row * 512;
    float4 h0 = *(const float4*)(hrow + lane * 8);
    float4 h1 = *(const float4*)(hrow + lane * 8 + 4);
    for (int k2 = 0; k2 < KTAG; ++k2) {
        const float* wr = Wout + (size_t)k2 * 512 + lane * 8;
        float4 w0 = *(const float4*)wr;
        float4 w1 = *(const float4*)(wr + 4);
        float p = h0.x * w0.x + h0.y * w0.y + h0.z * w0.z + h0.w * w0.w
                + h1.x * w1.x + h1.y * w1.y + h1.z * w1.z + h1.w * w1.w;
#pragma unroll
        for (int off = 32; off; off >>= 1) p += __shfl_down(p, off);
        if (lane == 0) feats[row * KTAG + k2] = p + bout[k2];
    }
}

// ---------------------------------------------------------------------------
// K4: Viterbi DP + backtrace. One wave per batch. 8-step feats prefetch ring.
// ---------------------------------------------------------------------------
__global__ __launch_bounds__(64) void viterbi_kernel(
    const float* __restrict__ feats, const float* __restrict__ trans,
    const int* __restrict__ slen, float* __restrict__ out) {
    int b = blockIdx.x;
    int lane = threadIdx.x;
    __shared__ unsigned char bp[TLEN][KTAG];

    int len = slen[b];
    float tr[KTAG];
#pragma unroll
    for (int p = 0; p < KTAG; ++p) tr[p] = 0.f;
    if (lane < KTAG) {
#pragma unroll
        for (int p = 0; p < KTAG; ++p) tr[p] = trans[lane * KTAG + p];
    }
    float tstop = (lane < KTAG) ? trans[STOP_TAG * KTAG + lane] : NEGV;
    float dp = (lane == START_TAG) ? 0.f : NEGV;

    float fb[8];
#pragma unroll
    for (int k = 0; k < 8; ++k)
        fb[k] = (lane < KTAG) ? feats[((size_t)k * BATCH + b) * KTAG + lane] : 0.f;

    for (int t0 = 0; t0 < TLEN; t0 += 8) {
#pragma unroll
        for (int u = 0; u < 8; ++u) {
            int t = t0 + u;
            float ftc = fb[u];
            int tn = t + 8;
            fb[u] = (tn < TLEN && lane < KTAG)
                        ? feats[((size_t)tn * BATCH + b) * KTAG + lane] : 0.f;
            float best = -1e30f;
            int arg = 0;
#pragma unroll
            for (int p = 0; p < KTAG; ++p) {
                float dpp = __shfl(dp, p);
                float sc = dpp + tr[p];
                if (sc > best) { best = sc; arg = p; }
            }
            bool m = (t < len);
            if (lane < KTAG) {
                dp = m ? (best + ftc) : dp;
                bp[t][lane] = (unsigned char)(m ? arg : lane);
            }
        }
    }

    float term = dp + tstop;
    float bbest = -1e30f;
    int barg = 0;
#pragma unroll
    for (int p = 0; p < KTAG; ++p) {
        float v = __shfl(term, p);
        if (v > bbest) { bbest = v; barg = p; }
    }
    if (lane == 0) {
        out[b] = bbest;
        float* path = out + BATCH + (size_t)b * TLEN;
        int tag = barg;
        for (int t = TLEN - 1; t >= 0; --t) {
            path[t] = (float)tag;
            tag = bp[t][tag];
        }
    }
}

// ---------------------------------------------------------------------------
extern "C" void kernel_launch(void* const* d_in, const int* in_sizes, int n_in,
                              void* d_out, int out_size, void* d_ws, size_t ws_size,
                              hipStream_t stream) {
    const int*   sentence = (const int*)d_in[0];
    const int*   slen     = (const int*)d_in[1];
    const float* emb      = (const float*)d_in[2];
    const float* Wf_ih    = (const float*)d_in[3];
    const float* Wf_hh    = (const float*)d_in[4];
    const float* bf_ih    = (const float*)d_in[5];
    const float* bf_hh    = (const float*)d_in[6];
    const float* Wb_ih    = (const float*)d_in[7];
    const float* Wb_hh    = (const float*)d_in[8];
    const float* bb_ih    = (const float*)d_in[9];
    const float* bb_hh    = (const float*)d_in[10];
    const float* W_out    = (const float*)d_in[11];
    const float* b_out    = (const float*)d_in[12];
    const float* trans    = (const float*)d_in[13];
    float* out = (float*)d_out;

    char* ws = (char*)d_ws;
    float* xf    = (float*)(ws);                       // 134,217,728 B
    float* xb    = (float*)(ws + 134217728ull);        // 134,217,728 B
    float* hcat  = (float*)(ws + 268435456ull);        //  67,108,864 B
    float* feats = (float*)(ws + 335544320ull);        //   1,572,864 B

    // sentinel-fill hcat: 0xFFFFFFFF = -NaN, unreachable for tanh-bounded h
    hipMemsetAsync(hcat, 0xFF, 67108864ull, stream);
    hipLaunchKernelGGL(proj_kernel, dim3(256, 16), dim3(256), 0, stream,
                       sentence, emb, Wf_ih, Wb_ih, bf_ih, bf_hh, bb_ih, bb_hh, xf, xb);
    hipLaunchKernelGGL(lstm_scan6, dim3(256), dim3(256), 0, stream,
                       xf, xb, Wf_hh, Wb_hh, hcat);
    hipLaunchKernelGGL(feats_kernel, dim3(8192), dim3(256), 0, stream,
                       hcat, W_out, b_out, feats);
    hipLaunchKernelGGL(viterbi_kernel, dim3(64), dim3(64), 0, stream,
                       feats, trans, slen, out);
}